// Round 7
// baseline (132.231 us; speedup 1.0000x reference)
//
#include <hip/hip_runtime.h>
#include <hip/hip_bf16.h>

#define IN_SZ   256
#define OUT_SZ  256
#define NNZ_C   2048
#define NB      16      // nodes per block (fallback kernel)
#define BM      64      // GEMM rows per block
#define BK      64      // K per tile (f32); LDS row = 256 B = 16 granules

typedef __attribute__((ext_vector_type(8))) short bf16x8;
typedef __attribute__((ext_vector_type(4))) float f32x4;

static __device__ __forceinline__ short f2bf(float f) {
    __hip_bfloat16 h = __float2bfloat16(f);
    return (short)__builtin_bit_cast(unsigned short, h);
}

// ---------------- builder: one block per output column j (proven r5/r6) ---
// Binary-search segment of sorted M, accumulate row j of W^T in LDS (f32
// atomics fold duplicate (j,m)), scatter bf16 into MFMA B-fragment layout:
//   chunk c = (((w*4+n)*4+kt)*2+kf)*64 + lane holds 8 consecutive k,
//   j = w*64+n*16+(lane&15), k = kt*64+kf*32+(lane>>4)*8+e.

__global__ void build_w(const float* __restrict__ scale,
                        const int*   __restrict__ M_in,
                        const int*   __restrict__ M,
                        unsigned short* __restrict__ wb)
{
    __shared__ float row[IN_SZ];
    const int j = blockIdx.x;
    const int t = threadIdx.x;          // 64 threads

#pragma unroll
    for (int i = t; i < IN_SZ; i += 64) row[i] = 0.f;

    int lo = 0, hi = NNZ_C;
    while (lo < hi) { int mid = (lo + hi) >> 1; if (M[mid] < j)     lo  = mid + 1; else hi  = mid; }
    int lo2 = lo, hi2 = NNZ_C;
    while (lo2 < hi2) { int mid = (lo2 + hi2) >> 1; if (M[mid] < j + 1) lo2 = mid + 1; else hi2 = mid; }

    __syncthreads();
    for (int k = lo + t; k < lo2; k += 64)
        atomicAdd(&row[M_in[k]], scale[k]);
    __syncthreads();

    const int wn = j >> 6, n = (j >> 4) & 3, l15 = j & 15;
#pragma unroll
    for (int kk = t; kk < IN_SZ; kk += 64) {
        int kt = kk >> 6, kf = (kk >> 5) & 1, lhi = (kk >> 3) & 3, e = kk & 7;
        int lane = lhi * 16 + l15;
        int c = (((wn * 4 + n) * 4 + kt) * 2 + kf) * 64 + lane;
        wb[c * 8 + e] = (unsigned short)f2bf(row[kk]);
    }
}

// ---------------- 3-buffer counted-vmcnt pipelined GEMM (T3/T4) -----------
// 1024 blocks x 256 thr (4 waves = 4 col groups, wave tile 64x64).
// A tile (64x64 f32 = 16 KB) DMA'd by global_load_lds, 16B-granule XOR
// swizzle g_phys = g ^ (row&7) on the GLOBAL source (LDS dest linear).
// 3 LDS buffers, stages kept 2-deep in flight; each phase waits a COUNTED
// vmcnt (stage issued two phases ago), never vmcnt(0), then raw s_barrier.
// Per-phase vmem issue order (pinned by "memory"-clobber asm at the phase
// boundary): [loadB: 8 ops][compute][stage: 4 ops] -> steady wait = 12.

__global__ __launch_bounds__(256, 3)
void gemm_pipe(const float* __restrict__ input,
               const bf16x8* __restrict__ wfrag,
               float* __restrict__ out)
{
    __shared__ float sA[3][BM * BK];    // 3 x 16 KB

    const int tid  = threadIdx.x;
    const int lane = tid & 63;
    const int w    = tid >> 6;          // wave id = col group 0..3
    const int l15  = lane & 15, lhi = lane >> 4;
    const long row0 = (long)blockIdx.x * BM;

    // 16 chunks of 1 KB per tile (4 rows each); 4 chunks per wave.
    auto stage = [&](int buf, int kt) {
#pragma unroll
        for (int it = 0; it < 4; ++it) {
            const int c = w * 4 + it;
            const int r = c * 4 + lhi;
            const int g = l15 ^ (r & 7);
            const float* src = input + (row0 + r) * IN_SZ + kt * BK + g * 4;
            __builtin_amdgcn_global_load_lds(
                (const __attribute__((address_space(1))) unsigned int*)src,
                (__attribute__((address_space(3))) unsigned int*)&sA[buf][c * 256],
                16, 0, 0);
        }
    };
    auto loadB = [&](bf16x8* dst, int kt) {
#pragma unroll
        for (int i = 0; i < 8; ++i)
            dst[i] = wfrag[(((w * 4 + (i >> 1)) * 4 + kt) * 2 + (i & 1)) * 64 + lane];
    };

    f32x4 acc[4][4];
#pragma unroll
    for (int m = 0; m < 4; ++m)
#pragma unroll
        for (int n = 0; n < 4; ++n)
            acc[m][n] = (f32x4){0.f, 0.f, 0.f, 0.f};

    auto compute = [&](int buf, const bf16x8* B) {
#pragma unroll
        for (int kf = 0; kf < 2; ++kf)
#pragma unroll
            for (int m = 0; m < 4; ++m) {
                const int r  = m * 16 + l15;
                const int g0 = kf * 8 + lhi * 2;
                f32x4 a0 = *(const f32x4*)&sA[buf][r * BK + (((g0    ) ^ (r & 7)) << 2)];
                f32x4 a1 = *(const f32x4*)&sA[buf][r * BK + (((g0 + 1) ^ (r & 7)) << 2)];
                bf16x8 u;
                u[0] = f2bf(a0[0]); u[1] = f2bf(a0[1]);
                u[2] = f2bf(a0[2]); u[3] = f2bf(a0[3]);
                u[4] = f2bf(a1[0]); u[5] = f2bf(a1[1]);
                u[6] = f2bf(a1[2]); u[7] = f2bf(a1[3]);
#pragma unroll
                for (int n = 0; n < 4; ++n)
                    acc[m][n] = __builtin_amdgcn_mfma_f32_16x16x32_bf16(
                        u, B[n * 2 + kf], acc[m][n], 0, 0, 0);
            }
    };

    bf16x8 Breg[2][8];

    // prologue: [stage0:4][loadB kt0:8][stage1:4] -> 16 outstanding
    stage(0, 0);
    loadB(Breg[0], 0);
    stage(1, 1);

    // phase 0: need stage0 done; newer = 8 (B kt0) + 4 (stage1) = 12
    asm volatile("s_waitcnt vmcnt(12)" ::: "memory");
    __builtin_amdgcn_s_barrier();
    __builtin_amdgcn_sched_barrier(0);
    loadB(Breg[1], 1);
    compute(0, Breg[0]);
    stage(2, 2);

    // phase 1: need stage1 done; newer = 8 (B kt1) + 4 (stage2) = 12
    asm volatile("s_waitcnt vmcnt(12)" ::: "memory");
    __builtin_amdgcn_s_barrier();
    __builtin_amdgcn_sched_barrier(0);
    loadB(Breg[0], 2);
    compute(1, Breg[1]);
    stage(0, 3);            // safe: barrier above proves all waves left buf0

    // phase 2: need stage2 done; newer = 8 (B kt2) + 4 (stage3) = 12
    asm volatile("s_waitcnt vmcnt(12)" ::: "memory");
    __builtin_amdgcn_s_barrier();
    __builtin_amdgcn_sched_barrier(0);
    loadB(Breg[1], 3);
    compute(2, Breg[0]);

    // phase 3: need stage3 done; newer = 8 (B kt3)
    asm volatile("s_waitcnt vmcnt(8)" ::: "memory");
    __builtin_amdgcn_s_barrier();
    __builtin_amdgcn_sched_barrier(0);
    compute(0, Breg[1]);

    // epilogue: C/D layout col = lane&15, row = (lane>>4)*4 + r (verified)
#pragma unroll
    for (int m = 0; m < 4; ++m) {
        long r0 = row0 + m * 16 + lhi * 4;
#pragma unroll
        for (int n = 0; n < 4; ++n) {
            int col = w * 64 + n * 16 + l15;
#pragma unroll
            for (int r = 0; r < 4; ++r)
                out[(r0 + r) * OUT_SZ + col] = acc[m][n][r];
        }
    }
}

// ---------------- fallback: round-1 sparse kernel ----------------

__global__ __launch_bounds__(256, 4)
void sparse_tp_kernel(const float* __restrict__ input,
                      const float* __restrict__ scale,
                      const int*   __restrict__ M_in,
                      const int*   __restrict__ M,
                      float*       __restrict__ out,
                      int N)
{
    __shared__ float s_in[NB * IN_SZ];
    __shared__ float s_scale[NNZ_C];
    __shared__ int   s_min[NNZ_C];
    __shared__ int   s_seg[OUT_SZ + 1];

    const int tid  = threadIdx.x;
    const int base = blockIdx.x * NB;

    {
        const float4* sc4  = reinterpret_cast<const float4*>(scale);
        const int4*   mi4  = reinterpret_cast<const int4*>(M_in);
        float4*       ssc4 = reinterpret_cast<float4*>(s_scale);
        int4*         smi4 = reinterpret_cast<int4*>(s_min);
        for (int v = tid; v < NNZ_C / 4; v += 256) { ssc4[v] = sc4[v]; smi4[v] = mi4[v]; }
    }
    {
        const float4* in4 = reinterpret_cast<const float4*>(input + (size_t)base * IN_SZ);
        float4*       si4 = reinterpret_cast<float4*>(s_in);
        for (int v = tid; v < NB * IN_SZ / 4; v += 256) {
            int row = v / (IN_SZ / 4);
            if (base + row < N) si4[v] = in4[v];
        }
    }
    {
        int j = tid, lo = 0, hi = NNZ_C;
        while (lo < hi) { int mid = (lo + hi) >> 1; if (M[mid] < j) lo = mid + 1; else hi = mid; }
        s_seg[j] = lo;
        if (tid == 0) s_seg[OUT_SZ] = NNZ_C;
    }
    __syncthreads();

    float acc[NB];
#pragma unroll
    for (int i = 0; i < NB; ++i) acc[i] = 0.f;

    const int j = tid;
    const int k1 = s_seg[j + 1];
    for (int k = s_seg[j]; k < k1; ++k) {
        const float s = s_scale[k];
        const int   m = s_min[k];
#pragma unroll
        for (int i = 0; i < NB; ++i) acc[i] += s * s_in[i * IN_SZ + m];
    }

    float* orow = out + (size_t)base * OUT_SZ + j;
#pragma unroll
    for (int i = 0; i < NB; ++i)
        if (base + i < N) orow[(size_t)i * OUT_SZ] = acc[i];
}

// ---------------- launcher ----------------

extern "C" void kernel_launch(void* const* d_in, const int* in_sizes, int n_in,
                              void* d_out, int out_size, void* d_ws, size_t ws_size,
                              hipStream_t stream)
{
    const float* input = (const float*)d_in[0];
    const float* scale = (const float*)d_in[1];
    const int*   M_in  = (const int*)d_in[2];
    const int*   M     = (const int*)d_in[3];
    float*       out   = (float*)d_out;

    const int N = in_sizes[0] / IN_SZ;

    if (ws_size >= (size_t)(128 * 1024) && (N % BM) == 0) {
        unsigned short* wb = (unsigned short*)d_ws;
        build_w  <<<OUT_SZ, 64, 0, stream>>>(scale, M_in, M, wb);
        gemm_pipe<<<N / BM, 256, 0, stream>>>(input, (const bf16x8*)wb, out);
    } else {
        sparse_tp_kernel<<<(N + NB - 1) / NB, 256, 0, stream>>>(input, scale, M_in, M, out, N);
    }
}